// Round 5
// baseline (622.447 us; speedup 1.0000x reference)
//
#include <hip/hip_runtime.h>
#include <math.h>

#define NN 1024
#define H 128
#define NL 4
#define NBLK 512

struct Params {
    const float *x, *embW, *embB, *lng, *lnb, *eW1, *eb1, *eW2, *eb2;
    const float *gcW, *gcb, *inW, *inb, *outPW, *outPb, *outW, *outb;
    float *aM, *bM, *adj, *g, *partial, *qkv, *Wt_in, *Wt_out;
    float *opart, *mpart, *lpart, *h2, *out;
    unsigned *cnt;
};

union SMem {
    struct { float xs[2][64]; float red[2][128]; float hs[2][128]; } emb;
    struct { float as_[32][132]; float bst[128][36]; float w2s[128]; } aj;
    struct { float adjs[2][16][65]; } sp;
    struct { float s[2][128]; } rm;
    struct { float kob[4][32][36]; float qT[32][36]; float pT[128][36];
             float marr[32]; float larr[32]; } at;
    struct { float p0[2][128]; } pl;
};

__global__ void k_init(unsigned* cnt) {
    if (threadIdx.x == 0) {
        __hip_atomic_store(cnt, 0u, __ATOMIC_RELEASE, __HIP_MEMORY_SCOPE_AGENT);
    }
}

// monotonic device-scope grid barrier: k-th barrier waits for cnt >= k*NBLK.
// A block cannot increment for barrier k+1 before being released from k,
// so cnt <= k*NBLK until all arrive: no reset needed within a launch.
__device__ __forceinline__ void gbar(unsigned* cnt, unsigned target) {
    __syncthreads();
    if (threadIdx.x == 0) {
        __hip_atomic_fetch_add(cnt, 1u, __ATOMIC_ACQ_REL, __HIP_MEMORY_SCOPE_AGENT);
        long spins = 0;
        while (__hip_atomic_load(cnt, __ATOMIC_ACQUIRE, __HIP_MEMORY_SCOPE_AGENT) < target) {
            __builtin_amdgcn_s_sleep(2);
            if (++spins > 8000000L) break;   // bounded: degrade, never hang
        }
    }
    __syncthreads();
}

__global__ __launch_bounds__(256, 2) void mega(Params P) {
    __shared__ SMem sm;
    const int B = blockIdx.x, T = threadIdx.x;
    const int half = T >> 7, t = T & 127;

    // ================= Phase A: weight transposes + embed (2 rows/block) ====
    {
        if (T < 128) {
            int gidx = B * 128 + T;
            if (gidx < 49152) P.Wt_in[gidx] = P.inW[(gidx % 384) * 128 + gidx / 384];
            else { int i2 = gidx - 49152; P.Wt_out[i2] = P.outPW[(i2 % 128) * 128 + i2 / 128]; }
        }
        int row = B * 2 + half;
        if (t < 64) sm.emb.xs[half][t] = P.x[row * 64 + t];
        __syncthreads();
        float acc = P.embB[t];
        #pragma unroll 8
        for (int k = 0; k < 64; ++k) acc = fmaf(sm.emb.xs[half][k], P.embW[k * H + t], acc);
        sm.emb.red[half][t] = acc; __syncthreads();
        for (int s = 64; s > 0; s >>= 1) { if (t < s) sm.emb.red[half][t] += sm.emb.red[half][t + s]; __syncthreads(); }
        float mu = sm.emb.red[half][0] * (1.f / H);
        __syncthreads();
        float d = acc - mu;
        sm.emb.red[half][t] = d * d; __syncthreads();
        for (int s = 64; s > 0; s >>= 1) { if (t < s) sm.emb.red[half][t] += sm.emb.red[half][t + s]; __syncthreads(); }
        float var = sm.emb.red[half][0] * (1.f / H);
        float hv = fmaxf(d * rsqrtf(var + 1e-5f) * P.lng[t] + P.lnb[t], 0.f);
        sm.emb.hs[half][t] = hv;
        __syncthreads();
        float aa = P.eb1[t], bb = 0.f, gg = 0.f;
        #pragma unroll 8
        for (int k = 0; k < H; ++k) {
            float hk = sm.emb.hs[half][k];
            aa = fmaf(hk, P.eW1[k * H + t], aa);
            bb = fmaf(hk, P.eW1[(H + k) * H + t], bb);
            gg = fmaf(hk, P.gcW[k * H + t], gg);
        }
        P.aM[row * H + t] = aa; P.bM[row * H + t] = bb; P.g[row * H + t] = gg;
    }
    gbar(P.cnt, NBLK * 1);

    // ================= Phase B: adjacency (2 tiles of 32x32 per block) ======
    for (int tt = 0; tt < 2; ++tt) {
        __syncthreads();
        int tile = B * 2 + tt;
        int i0 = (tile >> 5) * 32, j0 = (tile & 31) * 32;
        for (int idx = T; idx < 32 * H; idx += 256) {
            int r = idx >> 7, c = idx & 127;
            sm.aj.as_[r][c] = P.aM[(i0 + r) * H + c];
            sm.aj.bst[c][r] = P.bM[(j0 + r) * H + c];
        }
        if (T < H) sm.aj.w2s[T] = P.eW2[T];
        __syncthreads();
        int ti = T >> 3, tjg = T & 7;
        float a0 = 0.f, a1 = 0.f, a2 = 0.f, a3 = 0.f;
        const float eb2 = P.eb2[0];
        #pragma unroll 4
        for (int h = 0; h < H; ++h) {
            float av = sm.aj.as_[ti][h];
            float4 bv = *(const float4*)&sm.aj.bst[h][tjg * 4];
            float wh = sm.aj.w2s[h];
            a0 = fmaf(fmaxf(av + bv.x, 0.f), wh, a0);
            a1 = fmaf(fmaxf(av + bv.y, 0.f), wh, a1);
            a2 = fmaf(fmaxf(av + bv.z, 0.f), wh, a2);
            a3 = fmaf(fmaxf(av + bv.w, 0.f), wh, a3);
        }
        int i = i0 + ti, jb = j0 + tjg * 4;
        float4 ov;
        ov.x = (i == jb + 0) ? 0.f : 1.f / (1.f + __expf(-(a0 + eb2)));
        ov.y = (i == jb + 1) ? 0.f : 1.f / (1.f + __expf(-(a1 + eb2)));
        ov.z = (i == jb + 2) ? 0.f : 1.f / (1.f + __expf(-(a2 + eb2)));
        ov.w = (i == jb + 3) ? 0.f : 1.f / (1.f + __expf(-(a3 + eb2)));
        *(float4*)&P.adj[(size_t)i * NN + jb] = ov;
    }
    gbar(P.cnt, NBLK * 2);

    // ================= Phase C: 4 graph-conv layers =========================
    for (int l = 0; l < NL; ++l) {
        // ---- spmm: each 128-thread half handles one (16-row x 64-j) tile
        {
            int v = B * 2 + half, rb = v >> 4, p = v & 15;
            int r0 = rb * 16, j0 = p * 64;
            #pragma unroll
            for (int it = 0; it < 2; ++it) {
                int idx = t + it * 128;
                int r = idx >> 4, jg = idx & 15;
                float4 av = *(const float4*)&P.adj[(size_t)(r0 + r) * NN + j0 + jg * 4];
                sm.sp.adjs[half][r][jg * 4 + 0] = av.x;
                sm.sp.adjs[half][r][jg * 4 + 1] = av.y;
                sm.sp.adjs[half][r][jg * 4 + 2] = av.z;
                sm.sp.adjs[half][r][jg * 4 + 3] = av.w;
            }
            __syncthreads();
            int rg = t >> 5, c0 = (t & 31) * 4;
            float acc[4][4] = {};
            #pragma unroll 4
            for (int jj = 0; jj < 64; ++jj) {
                float ga[4];
                *(float4*)ga = *(const float4*)&P.g[(j0 + jj) * H + c0];
                #pragma unroll
                for (int r = 0; r < 4; ++r) {
                    float av = sm.sp.adjs[half][rg * 4 + r][jj];
                    #pragma unroll
                    for (int c = 0; c < 4; ++c) acc[r][c] = fmaf(av, ga[c], acc[r][c]);
                }
            }
            #pragma unroll
            for (int r = 0; r < 4; ++r) {
                float4 ov = {acc[r][0], acc[r][1], acc[r][2], acc[r][3]};
                *(float4*)&P.partial[((size_t)p * NN + r0 + rg * 4 + r) * H + c0] = ov;
            }
        }
        gbar(P.cnt, NBLK * (3 + 2 * l));
        // ---- reduce 16 partials + bias, then multiply by next W (or in_proj)
        {
            int row = B * 2 + half;
            float vv = P.gcb[l * H + t];
            #pragma unroll
            for (int p = 0; p < 16; ++p) vv += P.partial[(size_t)p * NN * H + row * H + t];
            sm.rm.s[half][t] = vv;
            __syncthreads();
            if (l < NL - 1) {
                const float* W = P.gcW + (size_t)(l + 1) * H * H;
                float acc = 0.f;
                #pragma unroll 8
                for (int k = 0; k < H; ++k) acc = fmaf(sm.rm.s[half][k], W[k * H + t], acc);
                P.g[row * H + t] = acc;
            } else {
                #pragma unroll
                for (int it = 0; it < 3; ++it) {
                    int c = t + it * 128;
                    float acc = P.inb[c];
                    #pragma unroll 8
                    for (int k = 0; k < H; ++k) acc = fmaf(sm.rm.s[half][k], P.Wt_in[k * 384 + c], acc);
                    P.qkv[row * 384 + c] = acc;
                }
            }
        }
        gbar(P.cnt, NBLK * (4 + 2 * l));
    }

    // ================= Phase D: split-K attention (2 virtual tiles/block) ===
    for (int tt = 0; tt < 2; ++tt) {
        __syncthreads();
        int v = B * 2 + tt;
        int i0 = (v & 31) * 32, head = (v >> 5) & 3, kp = v >> 7, j0 = kp * 128;
        int qoff = head * 32, koff = 128 + head * 32, voff = 256 + head * 32;
        float* kT = &sm.at.kob[0][0][0];
        const float scale = 0.17677669529663687f; // 1/sqrt(32)
        {
            int qi = T >> 3, dg = T & 7;
            float4 qv = *(const float4*)&P.qkv[(i0 + qi) * 384 + qoff + dg * 4];
            sm.at.qT[dg * 4 + 0][qi] = qv.x * scale;
            sm.at.qT[dg * 4 + 1][qi] = qv.y * scale;
            sm.at.qT[dg * 4 + 2][qi] = qv.z * scale;
            sm.at.qT[dg * 4 + 3][qi] = qv.w * scale;
        }
        #pragma unroll
        for (int it = 0; it < 4; ++it) {
            int idx = T + it * 256;
            int j = idx >> 3, dg = idx & 7;
            float4 kv = *(const float4*)&P.qkv[(j0 + j) * 384 + koff + dg * 4];
            kT[(dg * 4 + 0) * 132 + j] = kv.x;
            kT[(dg * 4 + 1) * 132 + j] = kv.y;
            kT[(dg * 4 + 2) * 132 + j] = kv.z;
            kT[(dg * 4 + 3) * 132 + j] = kv.w;
        }
        __syncthreads();
        int tq = T >> 5, tj = T & 31;
        float s[4][4] = {};
        #pragma unroll
        for (int kk = 0; kk < 32; ++kk) {
            float qa[4], ka[4];
            *(float4*)qa = *(float4*)&sm.at.qT[kk][tq * 4];
            *(float4*)ka = *(float4*)&kT[kk * 132 + tj * 4];
            #pragma unroll
            for (int a = 0; a < 4; ++a)
                #pragma unroll
                for (int b = 0; b < 4; ++b) s[a][b] = fmaf(qa[a], ka[b], s[a][b]);
        }
        #pragma unroll
        for (int a = 0; a < 4; ++a) {
            float mm = fmaxf(fmaxf(s[a][0], s[a][1]), fmaxf(s[a][2], s[a][3]));
            #pragma unroll
            for (int off = 16; off > 0; off >>= 1) mm = fmaxf(mm, __shfl_xor(mm, off));
            float ll = 0.f;
            #pragma unroll
            for (int b = 0; b < 4; ++b) { s[a][b] = __expf(s[a][b] - mm); ll += s[a][b]; }
            #pragma unroll
            for (int off = 16; off > 0; off >>= 1) ll += __shfl_xor(ll, off);
            if (tj == 0) { sm.at.marr[tq * 4 + a] = mm; sm.at.larr[tq * 4 + a] = ll; }
        }
        #pragma unroll
        for (int b = 0; b < 4; ++b)
            #pragma unroll
            for (int a = 0; a < 4; ++a) sm.at.pT[tj * 4 + b][tq * 4 + a] = s[a][b];
        __syncthreads();
        int qg = T >> 5, dg2 = (T >> 2) & 7, st = T & 3;
        float o[4][4] = {};
        #pragma unroll 4
        for (int jj = 0; jj < 32; ++jj) {
            int j = st * 32 + jj;
            float pa[4], va[4];
            *(float4*)pa = *(float4*)&sm.at.pT[j][qg * 4];
            *(float4*)va = *(const float4*)&P.qkv[(j0 + j) * 384 + voff + dg2 * 4];
            #pragma unroll
            for (int a = 0; a < 4; ++a)
                #pragma unroll
                for (int b = 0; b < 4; ++b) o[a][b] = fmaf(pa[a], va[b], o[a][b]);
        }
        __syncthreads();   // all pT reads done before kob (aliases kT) is overwritten
        #pragma unroll
        for (int a = 0; a < 4; ++a)
            #pragma unroll
            for (int b = 0; b < 4; ++b) sm.at.kob[st][qg * 4 + a][dg2 * 4 + b] = o[a][b];
        __syncthreads();
        {
            int q = T >> 3, d0 = (T & 7) * 4;
            float r0[4], r1[4], r2[4], r3[4];
            *(float4*)r0 = *(float4*)&sm.at.kob[0][q][d0];
            *(float4*)r1 = *(float4*)&sm.at.kob[1][q][d0];
            *(float4*)r2 = *(float4*)&sm.at.kob[2][q][d0];
            *(float4*)r3 = *(float4*)&sm.at.kob[3][q][d0];
            float4 ov;
            ov.x = (r0[0] + r1[0]) + (r2[0] + r3[0]);
            ov.y = (r0[1] + r1[1]) + (r2[1] + r3[1]);
            ov.z = (r0[2] + r1[2]) + (r2[2] + r3[2]);
            ov.w = (r0[3] + r1[3]) + (r2[3] + r3[3]);
            int pidx = head * 8 + kp;
            *(float4*)&P.opart[((size_t)pidx * NN + i0 + q) * 32 + d0] = ov;
            if (T < 32) {
                P.mpart[pidx * NN + i0 + T] = sm.at.marr[T];
                P.lpart[pidx * NN + i0 + T] = sm.at.larr[T];
            }
        }
    }
    gbar(P.cnt, NBLK * 11);

    // ================= Phase E: attention merge + out_proj (2 rows/block) ===
    {
        int row = B * 2 + half;
        int hd = t >> 5, d = t & 31;
        float mv[8], M = -1e30f;
        #pragma unroll
        for (int p = 0; p < 8; ++p) {
            mv[p] = P.mpart[(hd * 8 + p) * NN + row];
            M = fmaxf(M, mv[p]);
        }
        float L = 0.f, o = 0.f;
        #pragma unroll
        for (int p = 0; p < 8; ++p) {
            float w = __expf(mv[p] - M);
            L = fmaf(P.lpart[(hd * 8 + p) * NN + row], w, L);
            o = fmaf(P.opart[((size_t)(hd * 8 + p) * NN + row) * 32 + d], w, o);
        }
        sm.rm.s[half][t] = o / L;
        __syncthreads();
        float acc = P.outPb[t];
        #pragma unroll 8
        for (int k = 0; k < H; ++k) acc = fmaf(sm.rm.s[half][k], P.Wt_out[k * H + t], acc);
        P.h2[row * H + t] = acc;
    }
    gbar(P.cnt, NBLK * 12);

    // ================= Phase F: pool + head (block 0 only) ==================
    if (B == 0) {
        float s = 0.f;
        int rbase = half * 512;
        #pragma unroll 8
        for (int r = 0; r < 512; ++r) s += P.h2[(rbase + r) * H + t];
        sm.pl.p0[half][t] = s;
        __syncthreads();
        if (T < 128) sm.pl.p0[0][t] = (sm.pl.p0[0][t] + sm.pl.p0[1][t]) * (1.f / 1024.f);
        __syncthreads();
        if (T < 6) {
            float acc = P.outb[T];
            #pragma unroll 8
            for (int c = 0; c < H; ++c) acc = fmaf(sm.pl.p0[0][c], P.outW[c * 6 + T], acc);
            P.out[T] = (T == 1) ? fmaxf(acc, 0.f) : 1.f / (1.f + __expf(-acc));
        }
    }
}

extern "C" void kernel_launch(void* const* d_in, const int* in_sizes, int n_in,
                              void* d_out, int out_size, void* d_ws, size_t ws_size,
                              hipStream_t stream) {
    float* ws = (float*)d_ws;
    float* aM      = ws;                                 // 131072
    float* bM      = aM + NN * H;                        // 131072
    float* adj     = bM + NN * H;                        // 1048576
    float* g       = adj + (size_t)NN * NN;              // 131072
    float* partial = g + NN * H;                         // 16*131072
    float* qkv     = partial + (size_t)16 * NN * H;      // 393216
    float* Wt_in   = qkv + (size_t)NN * 384;             // 49152
    float* Wt_out  = Wt_in + 49152;                      // 16384
    unsigned* cnt  = (unsigned*)(Wt_out + 16384 + 256);  // barrier counter, isolated line

    Params p;
    p.x = (const float*)d_in[0];
    p.embW = (const float*)d_in[1];  p.embB = (const float*)d_in[2];
    p.lng = (const float*)d_in[3];   p.lnb = (const float*)d_in[4];
    p.eW1 = (const float*)d_in[5];   p.eb1 = (const float*)d_in[6];
    p.eW2 = (const float*)d_in[7];   p.eb2 = (const float*)d_in[8];
    p.gcW = (const float*)d_in[9];   p.gcb = (const float*)d_in[10];
    p.inW = (const float*)d_in[11];  p.inb = (const float*)d_in[12];
    p.outPW = (const float*)d_in[13]; p.outPb = (const float*)d_in[14];
    p.outW = (const float*)d_in[15]; p.outb = (const float*)d_in[16];
    p.aM = aM; p.bM = bM; p.adj = adj; p.g = g; p.partial = partial;
    p.qkv = qkv; p.Wt_in = Wt_in; p.Wt_out = Wt_out;
    // aliases (disjoint lifetimes):
    p.opart = adj;            // adj dead after last spmm
    p.mpart = aM;             // aM dead after phase B
    p.lpart = aM + 32 * NN;
    p.h2    = g;              // g dead after last spmm
    p.out = (float*)d_out;
    p.cnt = cnt;

    k_init<<<1, 64, 0, stream>>>(cnt);
    mega<<<dim3(NBLK), dim3(256), 0, stream>>>(p);
}

// Round 7
// 557.626 us; speedup vs baseline: 1.1162x; 1.1162x over previous
//
#include <hip/hip_runtime.h>
#include <math.h>

#define NN 1024
#define H 128
#define NL 4
#define NBLK 512

struct Params {
    const float *x, *embW, *embB, *lng, *lnb, *eW1, *eb1, *eW2, *eb2;
    const float *gcW, *gcb, *inW, *inb, *outPW, *outPb, *outW, *outb;
    float *aM, *bM, *adj, *g, *partial, *qkv, *Wt_in, *Wt_out;
    float *opart, *mpart, *lpart, *h2, *out;
    unsigned *cnt;
};

union SMem {
    struct { float xs[2][64]; float red[2][128]; float hs[2][128]; } emb;
    struct { float as_[32][132]; float bst[128][36]; float w2s[128]; } aj;
    struct { float adjs[2][16][65]; } sp;
    struct { float s[2][128]; } rm;
    struct { float kob[4][32][36]; float qT[32][36]; float pT[128][36];
             float marr[32]; float larr[32]; } at;
    struct { float p0[2][128]; } pl;
};

__global__ void k_init(unsigned* cnt) {
    if (threadIdx.x == 0) {
        __hip_atomic_store(cnt, 0u, __ATOMIC_RELEASE, __HIP_MEMORY_SCOPE_AGENT);
    }
}

// monotonic grid barrier, OCKL-style: release-RMW on arrival, RELAXED polls
// (no per-poll cache invalidate), one acquire fence after release observed.
__device__ __forceinline__ void gbar(unsigned* cnt, unsigned target) {
    __syncthreads();
    if (threadIdx.x == 0) {
        __hip_atomic_fetch_add(cnt, 1u, __ATOMIC_RELEASE, __HIP_MEMORY_SCOPE_AGENT);
        long spins = 0;
        while (__hip_atomic_load(cnt, __ATOMIC_RELAXED, __HIP_MEMORY_SCOPE_AGENT) < target) {
            __builtin_amdgcn_s_sleep(16);
            if (++spins > 500000L) break;   // bounded: degrade, never hang
        }
        __builtin_amdgcn_fence(__ATOMIC_ACQUIRE, "agent");
    }
    __syncthreads();
}

__global__ __launch_bounds__(256, 2) void mega(Params P) {
    __shared__ SMem sm;
    const int B = blockIdx.x, T = threadIdx.x;
    const int half = T >> 7, t = T & 127;

    // ================= Phase A: weight transposes + embed (2 rows/block) ====
    {
        if (T < 128) {
            int gidx = B * 128 + T;
            if (gidx < 49152) P.Wt_in[gidx] = P.inW[(gidx % 384) * 128 + gidx / 384];
            else { int i2 = gidx - 49152; P.Wt_out[i2] = P.outPW[(i2 % 128) * 128 + i2 / 128]; }
        }
        int row = B * 2 + half;
        if (t < 64) sm.emb.xs[half][t] = P.x[row * 64 + t];
        __syncthreads();
        float acc = P.embB[t];
        #pragma unroll 8
        for (int k = 0; k < 64; ++k) acc = fmaf(sm.emb.xs[half][k], P.embW[k * H + t], acc);
        sm.emb.red[half][t] = acc; __syncthreads();
        for (int s = 64; s > 0; s >>= 1) { if (t < s) sm.emb.red[half][t] += sm.emb.red[half][t + s]; __syncthreads(); }
        float mu = sm.emb.red[half][0] * (1.f / H);
        __syncthreads();
        float d = acc - mu;
        sm.emb.red[half][t] = d * d; __syncthreads();
        for (int s = 64; s > 0; s >>= 1) { if (t < s) sm.emb.red[half][t] += sm.emb.red[half][t + s]; __syncthreads(); }
        float var = sm.emb.red[half][0] * (1.f / H);
        float hv = fmaxf(d * rsqrtf(var + 1e-5f) * P.lng[t] + P.lnb[t], 0.f);
        sm.emb.hs[half][t] = hv;
        __syncthreads();
        float aa = P.eb1[t], bb = 0.f, gg = 0.f;
        #pragma unroll 8
        for (int k = 0; k < H; ++k) {
            float hk = sm.emb.hs[half][k];
            aa = fmaf(hk, P.eW1[k * H + t], aa);
            bb = fmaf(hk, P.eW1[(H + k) * H + t], bb);
            gg = fmaf(hk, P.gcW[k * H + t], gg);
        }
        P.aM[row * H + t] = aa; P.bM[row * H + t] = bb; P.g[row * H + t] = gg;
    }
    gbar(P.cnt, NBLK * 1);

    // ================= Phase B: adjacency (2 tiles of 32x32 per block) ======
    for (int tt = 0; tt < 2; ++tt) {
        __syncthreads();
        int tile = B * 2 + tt;
        int i0 = (tile >> 5) * 32, j0 = (tile & 31) * 32;
        for (int idx = T; idx < 32 * H; idx += 256) {
            int r = idx >> 7, c = idx & 127;
            sm.aj.as_[r][c] = P.aM[(i0 + r) * H + c];
            sm.aj.bst[c][r] = P.bM[(j0 + r) * H + c];
        }
        if (T < H) sm.aj.w2s[T] = P.eW2[T];
        __syncthreads();
        int ti = T >> 3, tjg = T & 7;
        float a0 = 0.f, a1 = 0.f, a2 = 0.f, a3 = 0.f;
        const float eb2 = P.eb2[0];
        #pragma unroll 4
        for (int h = 0; h < H; ++h) {
            float av = sm.aj.as_[ti][h];
            float4 bv = *(const float4*)&sm.aj.bst[h][tjg * 4];
            float wh = sm.aj.w2s[h];
            a0 = fmaf(fmaxf(av + bv.x, 0.f), wh, a0);
            a1 = fmaf(fmaxf(av + bv.y, 0.f), wh, a1);
            a2 = fmaf(fmaxf(av + bv.z, 0.f), wh, a2);
            a3 = fmaf(fmaxf(av + bv.w, 0.f), wh, a3);
        }
        int i = i0 + ti, jb = j0 + tjg * 4;
        float4 ov;
        ov.x = (i == jb + 0) ? 0.f : 1.f / (1.f + __expf(-(a0 + eb2)));
        ov.y = (i == jb + 1) ? 0.f : 1.f / (1.f + __expf(-(a1 + eb2)));
        ov.z = (i == jb + 2) ? 0.f : 1.f / (1.f + __expf(-(a2 + eb2)));
        ov.w = (i == jb + 3) ? 0.f : 1.f / (1.f + __expf(-(a3 + eb2)));
        *(float4*)&P.adj[(size_t)i * NN + jb] = ov;
    }
    gbar(P.cnt, NBLK * 2);

    // ================= Phase C: 4 graph-conv layers =========================
    for (int l = 0; l < NL; ++l) {
        // ---- spmm: each 128-thread half handles one (16-row x 64-j) tile
        {
            int v = B * 2 + half, rb = v >> 4, p = v & 15;
            int r0 = rb * 16, j0 = p * 64;
            #pragma unroll
            for (int it = 0; it < 2; ++it) {
                int idx = t + it * 128;
                int r = idx >> 4, jg = idx & 15;
                float4 av = *(const float4*)&P.adj[(size_t)(r0 + r) * NN + j0 + jg * 4];
                sm.sp.adjs[half][r][jg * 4 + 0] = av.x;
                sm.sp.adjs[half][r][jg * 4 + 1] = av.y;
                sm.sp.adjs[half][r][jg * 4 + 2] = av.z;
                sm.sp.adjs[half][r][jg * 4 + 3] = av.w;
            }
            __syncthreads();
            int rg = t >> 5, c0 = (t & 31) * 4;
            float acc[4][4] = {};
            #pragma unroll 4
            for (int jj = 0; jj < 64; ++jj) {
                float ga[4];
                *(float4*)ga = *(const float4*)&P.g[(j0 + jj) * H + c0];
                #pragma unroll
                for (int r = 0; r < 4; ++r) {
                    float av = sm.sp.adjs[half][rg * 4 + r][jj];
                    #pragma unroll
                    for (int c = 0; c < 4; ++c) acc[r][c] = fmaf(av, ga[c], acc[r][c]);
                }
            }
            #pragma unroll
            for (int r = 0; r < 4; ++r) {
                float4 ov = {acc[r][0], acc[r][1], acc[r][2], acc[r][3]};
                *(float4*)&P.partial[((size_t)p * NN + r0 + rg * 4 + r) * H + c0] = ov;
            }
        }
        gbar(P.cnt, NBLK * (3 + 2 * l));
        // ---- reduce 16 partials + bias, then multiply by next W (or in_proj)
        {
            int row = B * 2 + half;
            float vv = P.gcb[l * H + t];
            #pragma unroll
            for (int p = 0; p < 16; ++p) vv += P.partial[(size_t)p * NN * H + row * H + t];
            sm.rm.s[half][t] = vv;
            __syncthreads();
            if (l < NL - 1) {
                const float* W = P.gcW + (size_t)(l + 1) * H * H;
                float acc = 0.f;
                #pragma unroll 8
                for (int k = 0; k < H; ++k) acc = fmaf(sm.rm.s[half][k], W[k * H + t], acc);
                P.g[row * H + t] = acc;
            } else {
                #pragma unroll
                for (int it = 0; it < 3; ++it) {
                    int c = t + it * 128;
                    float acc = P.inb[c];
                    #pragma unroll 8
                    for (int k = 0; k < H; ++k) acc = fmaf(sm.rm.s[half][k], P.Wt_in[k * 384 + c], acc);
                    P.qkv[row * 384 + c] = acc;
                }
            }
        }
        gbar(P.cnt, NBLK * (4 + 2 * l));
    }

    // ================= Phase D: split-K attention (2 virtual tiles/block) ===
    for (int tt = 0; tt < 2; ++tt) {
        __syncthreads();
        int v = B * 2 + tt;
        int i0 = (v & 31) * 32, head = (v >> 5) & 3, kp = v >> 7, j0 = kp * 128;
        int qoff = head * 32, koff = 128 + head * 32, voff = 256 + head * 32;
        float* kT = &sm.at.kob[0][0][0];
        const float scale = 0.17677669529663687f; // 1/sqrt(32)
        {
            int qi = T >> 3, dg = T & 7;
            float4 qv = *(const float4*)&P.qkv[(i0 + qi) * 384 + qoff + dg * 4];
            sm.at.qT[dg * 4 + 0][qi] = qv.x * scale;
            sm.at.qT[dg * 4 + 1][qi] = qv.y * scale;
            sm.at.qT[dg * 4 + 2][qi] = qv.z * scale;
            sm.at.qT[dg * 4 + 3][qi] = qv.w * scale;
        }
        #pragma unroll
        for (int it = 0; it < 4; ++it) {
            int idx = T + it * 256;
            int j = idx >> 3, dg = idx & 7;
            float4 kv = *(const float4*)&P.qkv[(j0 + j) * 384 + koff + dg * 4];
            kT[(dg * 4 + 0) * 132 + j] = kv.x;
            kT[(dg * 4 + 1) * 132 + j] = kv.y;
            kT[(dg * 4 + 2) * 132 + j] = kv.z;
            kT[(dg * 4 + 3) * 132 + j] = kv.w;
        }
        __syncthreads();
        int tq = T >> 5, tj = T & 31;
        float s[4][4] = {};
        #pragma unroll
        for (int kk = 0; kk < 32; ++kk) {
            float qa[4], ka[4];
            *(float4*)qa = *(float4*)&sm.at.qT[kk][tq * 4];
            *(float4*)ka = *(float4*)&kT[kk * 132 + tj * 4];
            #pragma unroll
            for (int a = 0; a < 4; ++a)
                #pragma unroll
                for (int b = 0; b < 4; ++b) s[a][b] = fmaf(qa[a], ka[b], s[a][b]);
        }
        #pragma unroll
        for (int a = 0; a < 4; ++a) {
            float mm = fmaxf(fmaxf(s[a][0], s[a][1]), fmaxf(s[a][2], s[a][3]));
            #pragma unroll
            for (int off = 16; off > 0; off >>= 1) mm = fmaxf(mm, __shfl_xor(mm, off));
            float ll = 0.f;
            #pragma unroll
            for (int b = 0; b < 4; ++b) { s[a][b] = __expf(s[a][b] - mm); ll += s[a][b]; }
            #pragma unroll
            for (int off = 16; off > 0; off >>= 1) ll += __shfl_xor(ll, off);
            if (tj == 0) { sm.at.marr[tq * 4 + a] = mm; sm.at.larr[tq * 4 + a] = ll; }
        }
        #pragma unroll
        for (int b = 0; b < 4; ++b)
            #pragma unroll
            for (int a = 0; a < 4; ++a) sm.at.pT[tj * 4 + b][tq * 4 + a] = s[a][b];
        __syncthreads();
        int qg = T >> 5, dg2 = (T >> 2) & 7, st = T & 3;
        float o[4][4] = {};
        #pragma unroll 4
        for (int jj = 0; jj < 32; ++jj) {
            int j = st * 32 + jj;
            float pa[4], va[4];
            *(float4*)pa = *(float4*)&sm.at.pT[j][qg * 4];
            *(float4*)va = *(const float4*)&P.qkv[(j0 + j) * 384 + voff + dg2 * 4];
            #pragma unroll
            for (int a = 0; a < 4; ++a)
                #pragma unroll
                for (int b = 0; b < 4; ++b) o[a][b] = fmaf(pa[a], va[b], o[a][b]);
        }
        __syncthreads();   // all pT reads done before kob (aliases kT) is overwritten
        #pragma unroll
        for (int a = 0; a < 4; ++a)
            #pragma unroll
            for (int b = 0; b < 4; ++b) sm.at.kob[st][qg * 4 + a][dg2 * 4 + b] = o[a][b];
        __syncthreads();
        {
            int q = T >> 3, d0 = (T & 7) * 4;
            float r0[4], r1[4], r2[4], r3[4];
            *(float4*)r0 = *(float4*)&sm.at.kob[0][q][d0];
            *(float4*)r1 = *(float4*)&sm.at.kob[1][q][d0];
            *(float4*)r2 = *(float4*)&sm.at.kob[2][q][d0];
            *(float4*)r3 = *(float4*)&sm.at.kob[3][q][d0];
            float4 ov;
            ov.x = (r0[0] + r1[0]) + (r2[0] + r3[0]);
            ov.y = (r0[1] + r1[1]) + (r2[1] + r3[1]);
            ov.z = (r0[2] + r1[2]) + (r2[2] + r3[2]);
            ov.w = (r0[3] + r1[3]) + (r2[3] + r3[3]);
            int pidx = head * 8 + kp;
            *(float4*)&P.opart[((size_t)pidx * NN + i0 + q) * 32 + d0] = ov;
            if (T < 32) {
                P.mpart[pidx * NN + i0 + T] = sm.at.marr[T];
                P.lpart[pidx * NN + i0 + T] = sm.at.larr[T];
            }
        }
    }
    gbar(P.cnt, NBLK * 11);

    // ================= Phase E: attention merge + out_proj (2 rows/block) ===
    {
        int row = B * 2 + half;
        int hd = t >> 5, d = t & 31;
        float mv[8], M = -1e30f;
        #pragma unroll
        for (int p = 0; p < 8; ++p) {
            mv[p] = P.mpart[(hd * 8 + p) * NN + row];
            M = fmaxf(M, mv[p]);
        }
        float L = 0.f, o = 0.f;
        #pragma unroll
        for (int p = 0; p < 8; ++p) {
            float w = __expf(mv[p] - M);
            L = fmaf(P.lpart[(hd * 8 + p) * NN + row], w, L);
            o = fmaf(P.opart[((size_t)(hd * 8 + p) * NN + row) * 32 + d], w, o);
        }
        sm.rm.s[half][t] = o / L;
        __syncthreads();
        float acc = P.outPb[t];
        #pragma unroll 8
        for (int k = 0; k < H; ++k) acc = fmaf(sm.rm.s[half][k], P.Wt_out[k * H + t], acc);
        P.h2[row * H + t] = acc;
    }
    gbar(P.cnt, NBLK * 12);

    // ================= Phase F: pool + head (block 0 only) ==================
    if (B == 0) {
        float s = 0.f;
        int rbase = half * 512;
        #pragma unroll 8
        for (int r = 0; r < 512; ++r) s += P.h2[(rbase + r) * H + t];
        sm.pl.p0[half][t] = s;
        __syncthreads();
        if (T < 128) sm.pl.p0[0][t] = (sm.pl.p0[0][t] + sm.pl.p0[1][t]) * (1.f / 1024.f);
        __syncthreads();
        if (T < 6) {
            float acc = P.outb[T];
            #pragma unroll 8
            for (int c = 0; c < H; ++c) acc = fmaf(sm.pl.p0[0][c], P.outW[c * 6 + T], acc);
            P.out[T] = (T == 1) ? fmaxf(acc, 0.f) : 1.f / (1.f + __expf(-acc));
        }
    }
}

extern "C" void kernel_launch(void* const* d_in, const int* in_sizes, int n_in,
                              void* d_out, int out_size, void* d_ws, size_t ws_size,
                              hipStream_t stream) {
    float* ws = (float*)d_ws;
    float* aM      = ws;                                 // 131072
    float* bM      = aM + NN * H;                        // 131072
    float* adj     = bM + NN * H;                        // 1048576
    float* g       = adj + (size_t)NN * NN;              // 131072
    float* partial = g + NN * H;                         // 16*131072
    float* qkv     = partial + (size_t)16 * NN * H;      // 393216
    float* Wt_in   = qkv + (size_t)NN * 384;             // 49152
    float* Wt_out  = Wt_in + 49152;                      // 16384
    unsigned* cnt  = (unsigned*)(Wt_out + 16384 + 256);  // barrier counter, isolated line

    Params p;
    p.x = (const float*)d_in[0];
    p.embW = (const float*)d_in[1];  p.embB = (const float*)d_in[2];
    p.lng = (const float*)d_in[3];   p.lnb = (const float*)d_in[4];
    p.eW1 = (const float*)d_in[5];   p.eb1 = (const float*)d_in[6];
    p.eW2 = (const float*)d_in[7];   p.eb2 = (const float*)d_in[8];
    p.gcW = (const float*)d_in[9];   p.gcb = (const float*)d_in[10];
    p.inW = (const float*)d_in[11];  p.inb = (const float*)d_in[12];
    p.outPW = (const float*)d_in[13]; p.outPb = (const float*)d_in[14];
    p.outW = (const float*)d_in[15]; p.outb = (const float*)d_in[16];
    p.aM = aM; p.bM = bM; p.adj = adj; p.g = g; p.partial = partial;
    p.qkv = qkv; p.Wt_in = Wt_in; p.Wt_out = Wt_out;
    // aliases (disjoint lifetimes):
    p.opart = adj;            // adj dead after last spmm
    p.mpart = aM;             // aM dead after phase B
    p.lpart = aM + 32 * NN;
    p.h2    = g;              // g dead after last spmm
    p.out = (float*)d_out;
    p.cnt = cnt;

    k_init<<<1, 64, 0, stream>>>(cnt);
    mega<<<dim3(NBLK), dim3(256), 0, stream>>>(p);
}

// Round 8
// 384.482 us; speedup vs baseline: 1.6189x; 1.4503x over previous
//
#include <hip/hip_runtime.h>
#include <math.h>

#define NN 1024
#define H 128
#define NL 4
#define NBLK 512
#define CNT_SLOTS (129 * 64)   // 64 arrive + 1 master + 64 go, 256B-spaced

struct Params {
    const float *x, *embW, *embB, *lng, *lnb, *eW1, *eb1, *eW2, *eb2;
    const float *gcW, *gcb, *inW, *inb, *outPW, *outPb, *outW, *outb;
    float *aM, *bM, *adj, *g, *partial, *qkv, *Wt_in, *Wt_out;
    float *opart, *mpart, *lpart, *h2, *out;
    unsigned *cnt;
};

union SMem {
    struct { float xs[2][64]; float red[2][128]; float hs[2][128]; } emb;
    struct { float as_[32][132]; float bst[128][36]; float w2s[128]; } aj;
    struct { float adjs[2][16][65]; } sp;
    struct { float s[2][128]; } rm;
    struct { float kob[4][32][36]; float qT[32][36]; float pT[128][36];
             float marr[32]; float larr[32]; } at;
    struct { float p0[2][128]; } pl;
};

__global__ void k_init(unsigned* cnt) {
    for (int i = threadIdx.x; i < CNT_SLOTS; i += blockDim.x) cnt[i] = 0u;
}

// hierarchical grid barrier: 64 spaced arrive-lines (8 RMWs each) ->
// 64 leaders RMW master -> leaders store per-group go flag (8 pollers/line).
// All polls RELAXED; one agent acquire fence at exit.
__device__ __forceinline__ void gbarh(unsigned* base, unsigned epoch) {
    __syncthreads();
    if (threadIdx.x == 0) {
        const int B = blockIdx.x;
        const int g = B & 63;
        unsigned* arrive = base + g * 64;
        unsigned* master = base + 64 * 64;
        unsigned* go     = base + (65 + g) * 64;
        __hip_atomic_fetch_add(arrive, 1u, __ATOMIC_RELEASE, __HIP_MEMORY_SCOPE_AGENT);
        long spins = 0;
        if (B < 64) {          // leader of group B
            while (__hip_atomic_load(arrive, __ATOMIC_RELAXED, __HIP_MEMORY_SCOPE_AGENT) < 8u * epoch) {
                if (++spins > 4000000L) break;     // bounded: degrade, never hang
            }
            __hip_atomic_fetch_add(master, 1u, __ATOMIC_RELEASE, __HIP_MEMORY_SCOPE_AGENT);
            while (__hip_atomic_load(master, __ATOMIC_RELAXED, __HIP_MEMORY_SCOPE_AGENT) < 64u * epoch) {
                if (++spins > 4000000L) break;
            }
            __hip_atomic_store(go, epoch, __ATOMIC_RELEASE, __HIP_MEMORY_SCOPE_AGENT);
        } else {
            while (__hip_atomic_load(go, __ATOMIC_RELAXED, __HIP_MEMORY_SCOPE_AGENT) < epoch) {
                __builtin_amdgcn_s_sleep(1);
                if (++spins > 4000000L) break;
            }
        }
        __builtin_amdgcn_fence(__ATOMIC_ACQUIRE, "agent");
    }
    __syncthreads();
}

__global__ __launch_bounds__(256, 2) void mega(Params P) {
    __shared__ SMem sm;
    const int B = blockIdx.x, T = threadIdx.x;
    const int half = T >> 7, t = T & 127;

    // ================= Phase A: weight transposes + embed (2 rows/block) ====
    {
        if (T < 128) {
            int gidx = B * 128 + T;
            if (gidx < 49152) P.Wt_in[gidx] = P.inW[(gidx % 384) * 128 + gidx / 384];
            else { int i2 = gidx - 49152; P.Wt_out[i2] = P.outPW[(i2 % 128) * 128 + i2 / 128]; }
        }
        int row = B * 2 + half;
        if (t < 64) sm.emb.xs[half][t] = P.x[row * 64 + t];
        __syncthreads();
        float acc = P.embB[t];
        #pragma unroll 8
        for (int k = 0; k < 64; ++k) acc = fmaf(sm.emb.xs[half][k], P.embW[k * H + t], acc);
        sm.emb.red[half][t] = acc; __syncthreads();
        for (int s = 64; s > 0; s >>= 1) { if (t < s) sm.emb.red[half][t] += sm.emb.red[half][t + s]; __syncthreads(); }
        float mu = sm.emb.red[half][0] * (1.f / H);
        __syncthreads();
        float d = acc - mu;
        sm.emb.red[half][t] = d * d; __syncthreads();
        for (int s = 64; s > 0; s >>= 1) { if (t < s) sm.emb.red[half][t] += sm.emb.red[half][t + s]; __syncthreads(); }
        float var = sm.emb.red[half][0] * (1.f / H);
        float hv = fmaxf(d * rsqrtf(var + 1e-5f) * P.lng[t] + P.lnb[t], 0.f);
        sm.emb.hs[half][t] = hv;
        __syncthreads();
        float aa = P.eb1[t], bb = 0.f, gg = 0.f;
        #pragma unroll 8
        for (int k = 0; k < H; ++k) {
            float hk = sm.emb.hs[half][k];
            aa = fmaf(hk, P.eW1[k * H + t], aa);
            bb = fmaf(hk, P.eW1[(H + k) * H + t], bb);
            gg = fmaf(hk, P.gcW[k * H + t], gg);
        }
        P.aM[row * H + t] = aa; P.bM[row * H + t] = bb; P.g[row * H + t] = gg;
    }
    gbarh(P.cnt, 1);

    // ================= Phase B: adjacency (2 tiles of 32x32 per block) ======
    for (int tt = 0; tt < 2; ++tt) {
        __syncthreads();
        int tile = B * 2 + tt;
        int i0 = (tile >> 5) * 32, j0 = (tile & 31) * 32;
        for (int idx = T; idx < 32 * H; idx += 256) {
            int r = idx >> 7, c = idx & 127;
            sm.aj.as_[r][c] = P.aM[(i0 + r) * H + c];
            sm.aj.bst[c][r] = P.bM[(j0 + r) * H + c];
        }
        if (T < H) sm.aj.w2s[T] = P.eW2[T];
        __syncthreads();
        int ti = T >> 3, tjg = T & 7;
        float a0 = 0.f, a1 = 0.f, a2 = 0.f, a3 = 0.f;
        const float eb2 = P.eb2[0];
        #pragma unroll 4
        for (int h = 0; h < H; ++h) {
            float av = sm.aj.as_[ti][h];
            float4 bv = *(const float4*)&sm.aj.bst[h][tjg * 4];
            float wh = sm.aj.w2s[h];
            a0 = fmaf(fmaxf(av + bv.x, 0.f), wh, a0);
            a1 = fmaf(fmaxf(av + bv.y, 0.f), wh, a1);
            a2 = fmaf(fmaxf(av + bv.z, 0.f), wh, a2);
            a3 = fmaf(fmaxf(av + bv.w, 0.f), wh, a3);
        }
        int i = i0 + ti, jb = j0 + tjg * 4;
        float4 ov;
        ov.x = (i == jb + 0) ? 0.f : 1.f / (1.f + __expf(-(a0 + eb2)));
        ov.y = (i == jb + 1) ? 0.f : 1.f / (1.f + __expf(-(a1 + eb2)));
        ov.z = (i == jb + 2) ? 0.f : 1.f / (1.f + __expf(-(a2 + eb2)));
        ov.w = (i == jb + 3) ? 0.f : 1.f / (1.f + __expf(-(a3 + eb2)));
        *(float4*)&P.adj[(size_t)i * NN + jb] = ov;
    }
    gbarh(P.cnt, 2);

    // ================= Phase C: 4 graph-conv layers =========================
    for (int l = 0; l < NL; ++l) {
        // ---- spmm: each 128-thread half handles one (16-row x 64-j) tile
        {
            int v = B * 2 + half, rb = v >> 4, p = v & 15;
            int r0 = rb * 16, j0 = p * 64;
            #pragma unroll
            for (int it = 0; it < 2; ++it) {
                int idx = t + it * 128;
                int r = idx >> 4, jg = idx & 15;
                float4 av = *(const float4*)&P.adj[(size_t)(r0 + r) * NN + j0 + jg * 4];
                sm.sp.adjs[half][r][jg * 4 + 0] = av.x;
                sm.sp.adjs[half][r][jg * 4 + 1] = av.y;
                sm.sp.adjs[half][r][jg * 4 + 2] = av.z;
                sm.sp.adjs[half][r][jg * 4 + 3] = av.w;
            }
            __syncthreads();
            int rg = t >> 5, c0 = (t & 31) * 4;
            float acc[4][4] = {};
            #pragma unroll 4
            for (int jj = 0; jj < 64; ++jj) {
                float ga[4];
                *(float4*)ga = *(const float4*)&P.g[(j0 + jj) * H + c0];
                #pragma unroll
                for (int r = 0; r < 4; ++r) {
                    float av = sm.sp.adjs[half][rg * 4 + r][jj];
                    #pragma unroll
                    for (int c = 0; c < 4; ++c) acc[r][c] = fmaf(av, ga[c], acc[r][c]);
                }
            }
            #pragma unroll
            for (int r = 0; r < 4; ++r) {
                float4 ov = {acc[r][0], acc[r][1], acc[r][2], acc[r][3]};
                *(float4*)&P.partial[((size_t)p * NN + r0 + rg * 4 + r) * H + c0] = ov;
            }
        }
        gbarh(P.cnt, 3 + 2 * l);
        // ---- reduce 16 partials + bias, then multiply by next W (or in_proj)
        {
            int row = B * 2 + half;
            float vv = P.gcb[l * H + t];
            #pragma unroll
            for (int p = 0; p < 16; ++p) vv += P.partial[(size_t)p * NN * H + row * H + t];
            sm.rm.s[half][t] = vv;
            __syncthreads();
            if (l < NL - 1) {
                const float* W = P.gcW + (size_t)(l + 1) * H * H;
                float acc = 0.f;
                #pragma unroll 8
                for (int k = 0; k < H; ++k) acc = fmaf(sm.rm.s[half][k], W[k * H + t], acc);
                P.g[row * H + t] = acc;
            } else {
                #pragma unroll
                for (int it = 0; it < 3; ++it) {
                    int c = t + it * 128;
                    float acc = P.inb[c];
                    #pragma unroll 8
                    for (int k = 0; k < H; ++k) acc = fmaf(sm.rm.s[half][k], P.Wt_in[k * 384 + c], acc);
                    P.qkv[row * 384 + c] = acc;
                }
            }
        }
        gbarh(P.cnt, 4 + 2 * l);
    }

    // ================= Phase D: split-K attention (2 virtual tiles/block) ===
    for (int tt = 0; tt < 2; ++tt) {
        __syncthreads();
        int v = B * 2 + tt;
        int i0 = (v & 31) * 32, head = (v >> 5) & 3, kp = v >> 7, j0 = kp * 128;
        int qoff = head * 32, koff = 128 + head * 32, voff = 256 + head * 32;
        float* kT = &sm.at.kob[0][0][0];
        const float scale = 0.17677669529663687f; // 1/sqrt(32)
        {
            int qi = T >> 3, dg = T & 7;
            float4 qv = *(const float4*)&P.qkv[(i0 + qi) * 384 + qoff + dg * 4];
            sm.at.qT[dg * 4 + 0][qi] = qv.x * scale;
            sm.at.qT[dg * 4 + 1][qi] = qv.y * scale;
            sm.at.qT[dg * 4 + 2][qi] = qv.z * scale;
            sm.at.qT[dg * 4 + 3][qi] = qv.w * scale;
        }
        #pragma unroll
        for (int it = 0; it < 4; ++it) {
            int idx = T + it * 256;
            int j = idx >> 3, dg = idx & 7;
            float4 kv = *(const float4*)&P.qkv[(j0 + j) * 384 + koff + dg * 4];
            kT[(dg * 4 + 0) * 132 + j] = kv.x;
            kT[(dg * 4 + 1) * 132 + j] = kv.y;
            kT[(dg * 4 + 2) * 132 + j] = kv.z;
            kT[(dg * 4 + 3) * 132 + j] = kv.w;
        }
        __syncthreads();
        int tq = T >> 5, tj = T & 31;
        float s[4][4] = {};
        #pragma unroll
        for (int kk = 0; kk < 32; ++kk) {
            float qa[4], ka[4];
            *(float4*)qa = *(float4*)&sm.at.qT[kk][tq * 4];
            *(float4*)ka = *(float4*)&kT[kk * 132 + tj * 4];
            #pragma unroll
            for (int a = 0; a < 4; ++a)
                #pragma unroll
                for (int b = 0; b < 4; ++b) s[a][b] = fmaf(qa[a], ka[b], s[a][b]);
        }
        #pragma unroll
        for (int a = 0; a < 4; ++a) {
            float mm = fmaxf(fmaxf(s[a][0], s[a][1]), fmaxf(s[a][2], s[a][3]));
            #pragma unroll
            for (int off = 16; off > 0; off >>= 1) mm = fmaxf(mm, __shfl_xor(mm, off));
            float ll = 0.f;
            #pragma unroll
            for (int b = 0; b < 4; ++b) { s[a][b] = __expf(s[a][b] - mm); ll += s[a][b]; }
            #pragma unroll
            for (int off = 16; off > 0; off >>= 1) ll += __shfl_xor(ll, off);
            if (tj == 0) { sm.at.marr[tq * 4 + a] = mm; sm.at.larr[tq * 4 + a] = ll; }
        }
        #pragma unroll
        for (int b = 0; b < 4; ++b)
            #pragma unroll
            for (int a = 0; a < 4; ++a) sm.at.pT[tj * 4 + b][tq * 4 + a] = s[a][b];
        __syncthreads();
        int qg = T >> 5, dg2 = (T >> 2) & 7, st = T & 3;
        float o[4][4] = {};
        #pragma unroll 4
        for (int jj = 0; jj < 32; ++jj) {
            int j = st * 32 + jj;
            float pa[4], va[4];
            *(float4*)pa = *(float4*)&sm.at.pT[j][qg * 4];
            *(float4*)va = *(const float4*)&P.qkv[(j0 + j) * 384 + voff + dg2 * 4];
            #pragma unroll
            for (int a = 0; a < 4; ++a)
                #pragma unroll
                for (int b = 0; b < 4; ++b) o[a][b] = fmaf(pa[a], va[b], o[a][b]);
        }
        __syncthreads();   // all pT reads done before kob (aliases kT) is overwritten
        #pragma unroll
        for (int a = 0; a < 4; ++a)
            #pragma unroll
            for (int b = 0; b < 4; ++b) sm.at.kob[st][qg * 4 + a][dg2 * 4 + b] = o[a][b];
        __syncthreads();
        {
            int q = T >> 3, d0 = (T & 7) * 4;
            float r0[4], r1[4], r2[4], r3[4];
            *(float4*)r0 = *(float4*)&sm.at.kob[0][q][d0];
            *(float4*)r1 = *(float4*)&sm.at.kob[1][q][d0];
            *(float4*)r2 = *(float4*)&sm.at.kob[2][q][d0];
            *(float4*)r3 = *(float4*)&sm.at.kob[3][q][d0];
            float4 ov;
            ov.x = (r0[0] + r1[0]) + (r2[0] + r3[0]);
            ov.y = (r0[1] + r1[1]) + (r2[1] + r3[1]);
            ov.z = (r0[2] + r1[2]) + (r2[2] + r3[2]);
            ov.w = (r0[3] + r1[3]) + (r2[3] + r3[3]);
            int pidx = head * 8 + kp;
            *(float4*)&P.opart[((size_t)pidx * NN + i0 + q) * 32 + d0] = ov;
            if (T < 32) {
                P.mpart[pidx * NN + i0 + T] = sm.at.marr[T];
                P.lpart[pidx * NN + i0 + T] = sm.at.larr[T];
            }
        }
    }
    gbarh(P.cnt, 11);

    // ================= Phase E: attention merge + out_proj (2 rows/block) ===
    {
        int row = B * 2 + half;
        int hd = t >> 5, d = t & 31;
        float mv[8], M = -1e30f;
        #pragma unroll
        for (int p = 0; p < 8; ++p) {
            mv[p] = P.mpart[(hd * 8 + p) * NN + row];
            M = fmaxf(M, mv[p]);
        }
        float L = 0.f, o = 0.f;
        #pragma unroll
        for (int p = 0; p < 8; ++p) {
            float w = __expf(mv[p] - M);
            L = fmaf(P.lpart[(hd * 8 + p) * NN + row], w, L);
            o = fmaf(P.opart[((size_t)(hd * 8 + p) * NN + row) * 32 + d], w, o);
        }
        sm.rm.s[half][t] = o / L;
        __syncthreads();
        float acc = P.outPb[t];
        #pragma unroll 8
        for (int k = 0; k < H; ++k) acc = fmaf(sm.rm.s[half][k], P.Wt_out[k * H + t], acc);
        P.h2[row * H + t] = acc;
    }
    gbarh(P.cnt, 12);

    // ================= Phase F: pool + head (block 0 only) ==================
    if (B == 0) {
        float s = 0.f;
        int rbase = half * 512;
        #pragma unroll 8
        for (int r = 0; r < 512; ++r) s += P.h2[(rbase + r) * H + t];
        sm.pl.p0[half][t] = s;
        __syncthreads();
        if (T < 128) sm.pl.p0[0][t] = (sm.pl.p0[0][t] + sm.pl.p0[1][t]) * (1.f / 1024.f);
        __syncthreads();
        if (T < 6) {
            float acc = P.outb[T];
            #pragma unroll 8
            for (int c = 0; c < H; ++c) acc = fmaf(sm.pl.p0[0][c], P.outW[c * 6 + T], acc);
            P.out[T] = (T == 1) ? fmaxf(acc, 0.f) : 1.f / (1.f + __expf(-acc));
        }
    }
}

extern "C" void kernel_launch(void* const* d_in, const int* in_sizes, int n_in,
                              void* d_out, int out_size, void* d_ws, size_t ws_size,
                              hipStream_t stream) {
    float* ws = (float*)d_ws;
    float* aM      = ws;                                 // 131072
    float* bM      = aM + NN * H;                        // 131072
    float* adj     = bM + NN * H;                        // 1048576
    float* g       = adj + (size_t)NN * NN;              // 131072
    float* partial = g + NN * H;                         // 16*131072
    float* qkv     = partial + (size_t)16 * NN * H;      // 393216
    float* Wt_in   = qkv + (size_t)NN * 384;             // 49152
    float* Wt_out  = Wt_in + 49152;                      // 16384
    unsigned* cnt  = (unsigned*)(Wt_out + 16384 + 256);  // barrier region (33 KB)

    Params p;
    p.x = (const float*)d_in[0];
    p.embW = (const float*)d_in[1];  p.embB = (const float*)d_in[2];
    p.lng = (const float*)d_in[3];   p.lnb = (const float*)d_in[4];
    p.eW1 = (const float*)d_in[5];   p.eb1 = (const float*)d_in[6];
    p.eW2 = (const float*)d_in[7];   p.eb2 = (const float*)d_in[8];
    p.gcW = (const float*)d_in[9];   p.gcb = (const float*)d_in[10];
    p.inW = (const float*)d_in[11];  p.inb = (const float*)d_in[12];
    p.outPW = (const float*)d_in[13]; p.outPb = (const float*)d_in[14];
    p.outW = (const float*)d_in[15]; p.outb = (const float*)d_in[16];
    p.aM = aM; p.bM = bM; p.adj = adj; p.g = g; p.partial = partial;
    p.qkv = qkv; p.Wt_in = Wt_in; p.Wt_out = Wt_out;
    // aliases (disjoint lifetimes):
    p.opart = adj;            // adj dead after last spmm
    p.mpart = aM;             // aM dead after phase B
    p.lpart = aM + 32 * NN;
    p.h2    = g;              // g dead after last spmm
    p.out = (float*)d_out;
    p.cnt = cnt;

    k_init<<<1, 256, 0, stream>>>(cnt);
    mega<<<dim3(NBLK), dim3(256), 0, stream>>>(p);
}

// Round 9
// 179.217 us; speedup vs baseline: 3.4731x; 2.1453x over previous
//
#include <hip/hip_runtime.h>
#include <math.h>

#define NN 1024
#define IN_DIM 64
#define H 128
#define NL 4
#define HEADS 4
#define DH 32
#define KSPLIT 8   // attention j-chunks of 128
#define NSPLIT 16  // spmm j-chunks of 64

// ---------------- embed (4 rows/block): h=relu(LN(x@embW+b)); aM=h@W1a+eb1; bM=h@W1b; g0=h@gcW0
// plus in_proj/out_proj transposes as side work
__global__ __launch_bounds__(512) void k_embed(const float* __restrict__ x,
        const float* __restrict__ embW, const float* __restrict__ embB,
        const float* __restrict__ lng, const float* __restrict__ lnb,
        const float* __restrict__ eW1, const float* __restrict__ eb1,
        const float* __restrict__ gcW0,
        const float* __restrict__ inW, const float* __restrict__ outW,
        float* __restrict__ Wt_in, float* __restrict__ Wt_out,
        float* __restrict__ aM, float* __restrict__ bM, float* __restrict__ g0) {
    __shared__ float xs[4][IN_DIM];
    __shared__ float red[4][H];
    __shared__ float hs[4][H];
    int B = blockIdx.x, T = threadIdx.x;
    int half = T >> 7, t = T & 127;
    // side work: weight transposes (65536 elements over 256 blocks x 512 thr)
    int gidx = B * 512 + T;
    if (gidx < 49152) {
        Wt_in[gidx] = inW[(gidx % 384) * 128 + gidx / 384];
    } else if (gidx < 65536) {
        int i2 = gidx - 49152;
        Wt_out[i2] = outW[(i2 % 128) * 128 + i2 / 128];
    }
    if (T < 256) xs[T >> 6][T & 63] = x[(B * 4 + (T >> 6)) * IN_DIM + (T & 63)];
    __syncthreads();
    int row = B * 4 + half;
    float acc = embB[t];
    #pragma unroll 8
    for (int k = 0; k < IN_DIM; ++k) acc = fmaf(xs[half][k], embW[k * H + t], acc);
    red[half][t] = acc; __syncthreads();
    for (int s = 64; s > 0; s >>= 1) { if (t < s) red[half][t] += red[half][t + s]; __syncthreads(); }
    float mu = red[half][0] * (1.f / H);
    __syncthreads();
    float d = acc - mu;
    red[half][t] = d * d; __syncthreads();
    for (int s = 64; s > 0; s >>= 1) { if (t < s) red[half][t] += red[half][t + s]; __syncthreads(); }
    float var = red[half][0] * (1.f / H);
    float hv = fmaxf(d * rsqrtf(var + 1e-5f) * lng[t] + lnb[t], 0.f);
    hs[half][t] = hv;
    __syncthreads();
    float aa = eb1[t], bb = 0.f, gg = 0.f;
    #pragma unroll 8
    for (int k = 0; k < H; ++k) {
        float hk = hs[half][k];
        aa = fmaf(hk, eW1[k * H + t], aa);
        bb = fmaf(hk, eW1[(H + k) * H + t], bb);
        gg = fmaf(hk, gcW0[k * H + t], gg);
    }
    aM[row * H + t] = aa;
    bM[row * H + t] = bb;
    g0[row * H + t] = gg;
}

// ---------------- adj: 64x64 tile, aT/bT transposed LDS, float4 inner, h-chunked
__global__ __launch_bounds__(256) void k_adj(const float* __restrict__ aM, const float* __restrict__ bM,
        const float* __restrict__ w2, const float* __restrict__ eb2p, float* __restrict__ adj) {
    __shared__ float aT[32][68];
    __shared__ float bT[32][68];
    __shared__ float w2s[H];
    int i0 = blockIdx.y * 64, j0 = blockIdx.x * 64;
    int T = threadIdx.x;
    if (T < H) w2s[T] = w2[T];
    int tig = T >> 4, tjg = T & 15;
    float acc[4][4] = {};
    for (int hc = 0; hc < 4; ++hc) {
        __syncthreads();   // prev chunk compute done (first iter: covers w2s)
        #pragma unroll
        for (int it = 0; it < 2; ++it) {
            int f4i = T + it * 256;      // [0,512)
            int r = f4i >> 3, cc = f4i & 7;
            float4 av = *(const float4*)&aM[(i0 + r) * H + hc * 32 + cc * 4];
            float4 bv = *(const float4*)&bM[(j0 + r) * H + hc * 32 + cc * 4];
            aT[cc * 4 + 0][r] = av.x; aT[cc * 4 + 1][r] = av.y;
            aT[cc * 4 + 2][r] = av.z; aT[cc * 4 + 3][r] = av.w;
            bT[cc * 4 + 0][r] = bv.x; bT[cc * 4 + 1][r] = bv.y;
            bT[cc * 4 + 2][r] = bv.z; bT[cc * 4 + 3][r] = bv.w;
        }
        __syncthreads();
        #pragma unroll 8
        for (int hh = 0; hh < 32; ++hh) {
            float a4[4], b4[4];
            *(float4*)a4 = *(const float4*)&aT[hh][tig * 4];
            *(float4*)b4 = *(const float4*)&bT[hh][tjg * 4];
            float wh = w2s[hc * 32 + hh];
            #pragma unroll
            for (int r = 0; r < 4; ++r)
                #pragma unroll
                for (int c = 0; c < 4; ++c)
                    acc[r][c] = fmaf(fmaxf(a4[r] + b4[c], 0.f), wh, acc[r][c]);
        }
    }
    const float eb2 = eb2p[0];
    #pragma unroll
    for (int r = 0; r < 4; ++r) {
        int ia = i0 + tig * 4 + r;
        int jb = j0 + tjg * 4;
        float4 ov;
        ov.x = (ia == jb + 0) ? 0.f : 1.f / (1.f + __expf(-(acc[r][0] + eb2)));
        ov.y = (ia == jb + 1) ? 0.f : 1.f / (1.f + __expf(-(acc[r][1] + eb2)));
        ov.z = (ia == jb + 2) ? 0.f : 1.f / (1.f + __expf(-(acc[r][2] + eb2)));
        ov.w = (ia == jb + 3) ? 0.f : 1.f / (1.f + __expf(-(acc[r][3] + eb2)));
        *(float4*)&adj[(size_t)ia * NN + jb] = ov;
    }
}

// ---------------- spmm: partial[p][i][c] = sum_{j in 64-chunk p} adj[i][j]*g[j][c]
// adj staged TRANSPOSED: 1 LDS b128 + 1 global b128 per 16 FMA
__global__ __launch_bounds__(128) void k_spmm(const float* __restrict__ adj, const float* __restrict__ g,
        float* __restrict__ partial) {
    __shared__ float adjsT[64][17];
    int r0 = blockIdx.x * 16;
    int j0 = blockIdx.y * 64;
    int t = threadIdx.x;
    #pragma unroll
    for (int it = 0; it < 2; ++it) {
        int f4i = t + it * 128;          // [0,256)
        int r = f4i >> 4, jc = f4i & 15;
        float4 av = *(const float4*)&adj[(size_t)(r0 + r) * NN + j0 + jc * 4];
        adjsT[jc * 4 + 0][r] = av.x; adjsT[jc * 4 + 1][r] = av.y;
        adjsT[jc * 4 + 2][r] = av.z; adjsT[jc * 4 + 3][r] = av.w;
    }
    __syncthreads();
    int rg = t >> 5, cg = t & 31;
    int c0 = cg * 4;
    float acc[4][4] = {};
    #pragma unroll 4
    for (int jj = 0; jj < 64; ++jj) {
        float ga[4], a4[4];
        *(float4*)ga = *(const float4*)&g[(j0 + jj) * H + c0];
        *(float4*)a4 = *(const float4*)&adjsT[jj][rg * 4];
        #pragma unroll
        for (int r = 0; r < 4; ++r)
            #pragma unroll
            for (int c = 0; c < 4; ++c) acc[r][c] = fmaf(a4[r], ga[c], acc[r][c]);
    }
    #pragma unroll
    for (int r = 0; r < 4; ++r) {
        float4 ov = {acc[r][0], acc[r][1], acc[r][2], acc[r][3]};
        *(float4*)&partial[((size_t)blockIdx.y * NN + r0 + rg * 4 + r) * H + c0] = ov;
    }
}

// ---------------- fused 16-way reduce + bias + next matmul (H->H), 4 rows/block
__global__ __launch_bounds__(128) void k_redmat128(const float* __restrict__ partial,
        const float* __restrict__ bias, const float* __restrict__ W, float* __restrict__ outM) {
    __shared__ float s[4][H];
    int B = blockIdx.x, t = threadIdx.x;
    int row0 = B * 4;
    #pragma unroll
    for (int r = 0; r < 4; ++r) {
        float v = bias[t];
        #pragma unroll
        for (int p = 0; p < NSPLIT; ++p) v += partial[(size_t)p * NN * H + (row0 + r) * H + t];
        s[r][t] = v;
    }
    __syncthreads();
    float acc[4] = {};
    #pragma unroll 4
    for (int k = 0; k < H; ++k) {
        float wv = W[k * H + t];
        #pragma unroll
        for (int r = 0; r < 4; ++r) acc[r] = fmaf(s[r][k], wv, acc[r]);
    }
    #pragma unroll
    for (int r = 0; r < 4; ++r) outM[(row0 + r) * H + t] = acc[r];
}

// ---------------- fused 16-way reduce + bias + qkv projection (H->384), 4 rows/block
__global__ __launch_bounds__(384) void k_redmat384(const float* __restrict__ partial,
        const float* __restrict__ bias, const float* __restrict__ W,
        const float* __restrict__ bias2, float* __restrict__ outM) {
    __shared__ float s[4][H];
    int B = blockIdx.x, t = threadIdx.x;
    int row0 = B * 4;
    for (int idx = t; idx < 512; idx += 384) {
        int r = idx >> 7, c = idx & 127;
        float v = bias[c];
        #pragma unroll
        for (int p = 0; p < NSPLIT; ++p) v += partial[(size_t)p * NN * H + (row0 + r) * H + c];
        s[r][c] = v;
    }
    __syncthreads();
    float acc[4] = {bias2[t], bias2[t], bias2[t], bias2[t]};
    #pragma unroll 4
    for (int k = 0; k < H; ++k) {
        float wv = W[k * 384 + t];
        #pragma unroll
        for (int r = 0; r < 4; ++r) acc[r] = fmaf(s[r][k], wv, acc[r]);
    }
    #pragma unroll
    for (int r = 0; r < 4; ++r) outM[(row0 + r) * 384 + t] = acc[r];
}

// ---------------- split-K attention, register-tiled 4x4 QK and PV (verbatim R3)
__global__ __launch_bounds__(256) void k_attn_part(const float* __restrict__ qkv,
        float* __restrict__ opart, float* __restrict__ mpart, float* __restrict__ lpart) {
    __shared__ float kob[4][32][36];   // phase1: kT[32][132]; phase2: obuf[4][32][36]
    __shared__ float qT[32][36];
    __shared__ float pT[128][36];
    __shared__ float marr[32], larr[32];
    float* kT = &kob[0][0][0];
    const int t = threadIdx.x;
    const int head = blockIdx.y, kp = blockIdx.z;
    const int i0 = blockIdx.x * 32, j0 = kp * 128;
    const int qoff = head * DH, koff = H + head * DH, voff = 2 * H + head * DH;
    const float scale = 0.17677669529663687f; // 1/sqrt(32)
    {
        int qi = t >> 3, dg = t & 7;
        float4 qv = *(const float4*)&qkv[(i0 + qi) * 384 + qoff + dg * 4];
        qT[dg * 4 + 0][qi] = qv.x * scale;
        qT[dg * 4 + 1][qi] = qv.y * scale;
        qT[dg * 4 + 2][qi] = qv.z * scale;
        qT[dg * 4 + 3][qi] = qv.w * scale;
    }
    #pragma unroll
    for (int it = 0; it < 4; ++it) {
        int idx = t + it * 256;
        int j = idx >> 3, dg = idx & 7;
        float4 kv = *(const float4*)&qkv[(j0 + j) * 384 + koff + dg * 4];
        kT[(dg * 4 + 0) * 132 + j] = kv.x;
        kT[(dg * 4 + 1) * 132 + j] = kv.y;
        kT[(dg * 4 + 2) * 132 + j] = kv.z;
        kT[(dg * 4 + 3) * 132 + j] = kv.w;
    }
    __syncthreads();
    const int tq = t >> 5, tj = t & 31;
    float s[4][4] = {};
    #pragma unroll
    for (int kk = 0; kk < DH; ++kk) {
        float qa[4], ka[4];
        *(float4*)qa = *(float4*)&qT[kk][tq * 4];
        *(float4*)ka = *(float4*)&kT[kk * 132 + tj * 4];
        #pragma unroll
        for (int a = 0; a < 4; ++a)
            #pragma unroll
            for (int b = 0; b < 4; ++b) s[a][b] = fmaf(qa[a], ka[b], s[a][b]);
    }
    #pragma unroll
    for (int a = 0; a < 4; ++a) {
        float mm = fmaxf(fmaxf(s[a][0], s[a][1]), fmaxf(s[a][2], s[a][3]));
        #pragma unroll
        for (int off = 16; off > 0; off >>= 1) mm = fmaxf(mm, __shfl_xor(mm, off));
        float ll = 0.f;
        #pragma unroll
        for (int b = 0; b < 4; ++b) { s[a][b] = __expf(s[a][b] - mm); ll += s[a][b]; }
        #pragma unroll
        for (int off = 16; off > 0; off >>= 1) ll += __shfl_xor(ll, off);
        if (tj == 0) { marr[tq * 4 + a] = mm; larr[tq * 4 + a] = ll; }
    }
    #pragma unroll
    for (int b = 0; b < 4; ++b)
        #pragma unroll
        for (int a = 0; a < 4; ++a) pT[tj * 4 + b][tq * 4 + a] = s[a][b];
    __syncthreads();
    const int qg = t >> 5, dg2 = (t >> 2) & 7, st = t & 3;
    float o[4][4] = {};
    #pragma unroll 4
    for (int jj = 0; jj < 32; ++jj) {
        int j = st * 32 + jj;
        float pa[4], va[4];
        *(float4*)pa = *(float4*)&pT[j][qg * 4];
        *(float4*)va = *(const float4*)&qkv[(j0 + j) * 384 + voff + dg2 * 4];
        #pragma unroll
        for (int a = 0; a < 4; ++a)
            #pragma unroll
            for (int b = 0; b < 4; ++b) o[a][b] = fmaf(pa[a], va[b], o[a][b]);
    }
    __syncthreads();   // all pT/kT reads done before kob is overwritten
    #pragma unroll
    for (int a = 0; a < 4; ++a)
        #pragma unroll
        for (int b = 0; b < 4; ++b) kob[st][qg * 4 + a][dg2 * 4 + b] = o[a][b];
    __syncthreads();
    {
        int q = t >> 3, d0 = (t & 7) * 4;
        float r0[4], r1[4], r2[4], r3[4];
        *(float4*)r0 = *(float4*)&kob[0][q][d0];
        *(float4*)r1 = *(float4*)&kob[1][q][d0];
        *(float4*)r2 = *(float4*)&kob[2][q][d0];
        *(float4*)r3 = *(float4*)&kob[3][q][d0];
        float4 ov;
        ov.x = (r0[0] + r1[0]) + (r2[0] + r3[0]);
        ov.y = (r0[1] + r1[1]) + (r2[1] + r3[1]);
        ov.z = (r0[2] + r1[2]) + (r2[2] + r3[2]);
        ov.w = (r0[3] + r1[3]) + (r2[3] + r3[3]);
        int pidx = head * KSPLIT + kp;
        *(float4*)&opart[((size_t)pidx * NN + i0 + q) * DH + d0] = ov;
        if (t < 32) {
            mpart[pidx * NN + i0 + t] = marr[t];
            lpart[pidx * NN + i0 + t] = larr[t];
        }
    }
}

// ---------------- fused attention merge + out_proj (verbatim R3)
__global__ __launch_bounds__(128) void k_mergeproj(const float* __restrict__ opart,
        const float* __restrict__ mpart, const float* __restrict__ lpart,
        const float* __restrict__ Wt_out, const float* __restrict__ bias,
        float* __restrict__ h2) {
    __shared__ float s[H];
    int row = blockIdx.x, t = threadIdx.x;
    int head = t >> 5, d = t & 31;
    float mv[KSPLIT];
    float M = -1e30f;
    #pragma unroll
    for (int p = 0; p < KSPLIT; ++p) {
        mv[p] = mpart[(head * KSPLIT + p) * NN + row];
        M = fmaxf(M, mv[p]);
    }
    float L = 0.f, o = 0.f;
    #pragma unroll
    for (int p = 0; p < KSPLIT; ++p) {
        float w = __expf(mv[p] - M);
        L = fmaf(lpart[(head * KSPLIT + p) * NN + row], w, L);
        o = fmaf(opart[((size_t)(head * KSPLIT + p) * NN + row) * DH + d], w, o);
    }
    s[t] = o / L;
    __syncthreads();
    float acc = bias[t];
    #pragma unroll 8
    for (int k = 0; k < H; ++k) acc = fmaf(s[k], Wt_out[k * H + t], acc);
    h2[row * H + t] = acc;
}

// ---------------- pooling + head (verbatim R3)
__global__ void k_pool1(const float* __restrict__ h2, float* __restrict__ pp) {
    int b = blockIdx.x; // 0..31
    int t = threadIdx.x;
    int c = t & 127, rg = t >> 7;
    int r0 = b * 32 + rg * 16;
    float s = 0.f;
    #pragma unroll
    for (int r = 0; r < 16; ++r) s += h2[(r0 + r) * H + c];
    pp[(b * 2 + rg) * H + c] = s;
}

__global__ void k_pool2(const float* __restrict__ pp, const float* __restrict__ outW,
        const float* __restrict__ outB, float* __restrict__ out) {
    __shared__ float pooled[H];
    int t = threadIdx.x;
    float s = 0.f;
    #pragma unroll 8
    for (int p = 0; p < 64; ++p) s += pp[p * H + t];
    pooled[t] = s * (1.f / 1024.f);
    __syncthreads();
    if (t < 6) {
        float acc = outB[t];
        for (int c = 0; c < H; ++c) acc = fmaf(pooled[c], outW[c * 6 + t], acc);
        out[t] = (t == 1) ? fmaxf(acc, 0.f) : 1.f / (1.f + expf(-acc));
    }
}

extern "C" void kernel_launch(void* const* d_in, const int* in_sizes, int n_in,
                              void* d_out, int out_size, void* d_ws, size_t ws_size,
                              hipStream_t stream) {
    const float* x       = (const float*)d_in[0];
    const float* emb_W   = (const float*)d_in[1];
    const float* emb_b   = (const float*)d_in[2];
    const float* ln_g    = (const float*)d_in[3];
    const float* ln_b    = (const float*)d_in[4];
    const float* edge_W1 = (const float*)d_in[5];
    const float* edge_b1 = (const float*)d_in[6];
    const float* edge_W2 = (const float*)d_in[7];
    const float* edge_b2 = (const float*)d_in[8];
    const float* gc_W    = (const float*)d_in[9];
    const float* gc_b    = (const float*)d_in[10];
    const float* in_proj_W  = (const float*)d_in[11];
    const float* in_proj_b  = (const float*)d_in[12];
    const float* out_proj_W = (const float*)d_in[13];
    const float* out_proj_b = (const float*)d_in[14];
    const float* out_W   = (const float*)d_in[15];
    const float* out_b   = (const float*)d_in[16];
    float* out = (float*)d_out;

    float* ws = (float*)d_ws;
    float* aM      = ws;                    // 131072
    float* bM      = aM + NN * H;           // 131072
    float* adj     = bM + NN * H;           // 1048576
    float* g       = adj + (size_t)NN * NN; // 131072
    float* partial = g + NN * H;            // 16*131072 = 2097152
    float* qkv     = partial + (size_t)NSPLIT * NN * H;  // 393216
    float* Wt_in   = qkv + (size_t)NN * 384;// 49152
    float* Wt_out  = Wt_in + 128 * 384;     // 16384
    float* pp      = Wt_out + 128 * 128;    // 8192
    // aliases (lifetimes disjoint):
    float* opart = adj;          // 32*1024*32 = 1048576, adj dead after last spmm
    float* mpart = aM;           // 32768, aM dead after k_adj
    float* lpart = aM + 32 * NN; // 32768
    float* h2    = g;            // g dead after last redmat384

    k_embed<<<NN / 4, 512, 0, stream>>>(x, emb_W, emb_b, ln_g, ln_b, edge_W1, edge_b1,
                                        gc_W, in_proj_W, out_proj_W, Wt_in, Wt_out,
                                        aM, bM, g);
    k_adj<<<dim3(16, 16), 256, 0, stream>>>(aM, bM, edge_W2, edge_b2, adj);

    for (int l = 0; l < NL; ++l) {
        k_spmm<<<dim3(NN / 16, NSPLIT), 128, 0, stream>>>(adj, g, partial);
        if (l < NL - 1)
            k_redmat128<<<NN / 4, 128, 0, stream>>>(partial, gc_b + (size_t)l * H,
                                                    gc_W + (size_t)(l + 1) * H * H, g);
        else
            k_redmat384<<<NN / 4, 384, 0, stream>>>(partial, gc_b + (size_t)l * H,
                                                    Wt_in, in_proj_b, qkv);
    }

    k_attn_part<<<dim3(NN / 32, HEADS, KSPLIT), 256, 0, stream>>>(qkv, opart, mpart, lpart);
    k_mergeproj<<<NN, 128, 0, stream>>>(opart, mpart, lpart, Wt_out, out_proj_b, h2);
    k_pool1<<<32, 256, 0, stream>>>(h2, pp);
    k_pool2<<<1, 128, 0, stream>>>(pp, out_W, out_b, out);
}